// Round 1
// baseline (3440.390 us; speedup 1.0000x reference)
//
#include <hip/hip_runtime.h>

#define BATCH 64
#define SEQ   4096
#define ISZ   64
#define RSZ   128
constexpr float LEAK = 0.5f;

__device__ __forceinline__ float fast_tanh(float x) {
    float e = __expf(2.0f * x);
    return 1.0f - 2.0f / (e + 1.0f);
}

// ---------------------------------------------------------------------------
// Kernel 1: projection. out[row][r] = tanh(sum_j x[row][j] * w_in[r][j])
// rows = BATCH*SEQ flattened. 32 rows per block, 256 threads.
// Thread computes 4 rows x 4 consecutive r (16 outputs).
// ---------------------------------------------------------------------------
__global__ __launch_bounds__(256) void proj_kernel(
        const float* __restrict__ x, const float* __restrict__ w_in,
        float* __restrict__ out) {
    __shared__ float wT[ISZ][RSZ];   // 32 KB, transposed W_in: [j][r]
    __shared__ float xs[32][ISZ];    // 8 KB

    const int tid = threadIdx.x;

    // stage W_in transposed: W_in is [RSZ][ISZ] row-major
    for (int idx = tid; idx < RSZ * ISZ / 4; idx += 256) {
        const int r  = idx >> 4;          // ISZ/4 == 16
        const int j4 = (idx & 15) << 2;
        const float4 v = reinterpret_cast<const float4*>(w_in)[idx];
        wT[j4 + 0][r] = v.x; wT[j4 + 1][r] = v.y;
        wT[j4 + 2][r] = v.z; wT[j4 + 3][r] = v.w;
    }
    // stage 32 x-rows
    const long row0 = (long)blockIdx.x * 32;
    #pragma unroll
    for (int q = 0; q < 2; ++q) {
        const int idx = tid + q * 256;    // 512 float4 total
        reinterpret_cast<float4*>(&xs[0][0])[idx] =
            reinterpret_cast<const float4*>(x + row0 * ISZ)[idx];
    }
    __syncthreads();

    const int rq = tid & 31;              // 32 r-groups of 4
    const int rp = tid >> 5;              // 8 row-groups of 4
    const int r0 = rq << 2;
    const int ra = rp << 2;

    float acc[4][4] = {};
    #pragma unroll
    for (int j4 = 0; j4 < ISZ; j4 += 4) {
        float4 xv[4];
        #pragma unroll
        for (int m = 0; m < 4; ++m)
            xv[m] = *reinterpret_cast<const float4*>(&xs[ra + m][j4]);
        #pragma unroll
        for (int k = 0; k < 4; ++k) {
            const float4 w = *reinterpret_cast<const float4*>(&wT[j4 + k][r0]);
            #pragma unroll
            for (int m = 0; m < 4; ++m) {
                const float xm = k == 0 ? xv[m].x : k == 1 ? xv[m].y
                               : k == 2 ? xv[m].z : xv[m].w;
                acc[m][0] += xm * w.x; acc[m][1] += xm * w.y;
                acc[m][2] += xm * w.z; acc[m][3] += xm * w.w;
            }
        }
    }
    #pragma unroll
    for (int m = 0; m < 4; ++m) {
        float4 o;
        o.x = fast_tanh(acc[m][0]); o.y = fast_tanh(acc[m][1]);
        o.z = fast_tanh(acc[m][2]); o.w = fast_tanh(acc[m][3]);
        *reinterpret_cast<float4*>(&out[(row0 + ra + m) * RSZ + r0]) = o;
    }
}

// ---------------------------------------------------------------------------
// Kernel 2: sequential scan. One block per batch (64 blocks, 256 threads).
// Thread (wave, rs, kg): outputs r0..r0+3 (r0 = wave*32 + rs*4),
// K-slice k0..k0+15 (k0 = kg*16). W_res slice in registers (64 VGPRs).
// h double-buffered in LDS with 20-float group stride (bank-conflict-free).
// Reads u_t from io[b][t][:] (written by proj), overwrites with h_t in place.
// ---------------------------------------------------------------------------
__global__ __launch_bounds__(256) void scan_kernel(
        const float* __restrict__ w_res, float* __restrict__ io) {
    __shared__ float h[2][8 * 20];        // padded: addr = kg*20 + ksub

    const int tid  = threadIdx.x;
    const int lane = tid & 63;
    const int wave = tid >> 6;
    const int rs   = lane & 7;            // lane bits 0-2
    const int kg   = lane >> 3;           // lane bits 3-5 -> shfl masks 8,16,32
    const int r0   = wave * 32 + rs * 4;
    const int k0   = kg * 16;

    // W_res slice -> registers: rows r0..r0+3, cols k0..k0+15
    float w[4][16];
    #pragma unroll
    for (int rr = 0; rr < 4; ++rr) {
        #pragma unroll
        for (int kk = 0; kk < 16; kk += 4) {
            const float4 v = *reinterpret_cast<const float4*>(
                &w_res[(r0 + rr) * RSZ + k0 + kk]);
            w[rr][kk + 0] = v.x; w[rr][kk + 1] = v.y;
            w[rr][kk + 2] = v.z; w[rr][kk + 3] = v.w;
        }
    }

    for (int i = tid; i < 2 * 8 * 20; i += 256) (&h[0][0])[i] = 0.0f;

    float* const out = io + (long)blockIdx.x * (SEQ * RSZ);
    const bool writer = (kg == 0);
    const int  hoff   = kg * 20;                        // read offset (padded)
    const int  woff   = (r0 >> 4) * 20 + (r0 & 15);     // write offset (padded)

    float4 u_cur = {0, 0, 0, 0}, u_next = {0, 0, 0, 0};
    if (writer) u_cur = *reinterpret_cast<const float4*>(&out[r0]);
    __syncthreads();

    int cur = 0;
    for (int t = 0; t < SEQ; ++t) {
        if (writer && (t + 1 < SEQ))
            u_next = *reinterpret_cast<const float4*>(&out[(t + 1) * RSZ + r0]);

        float hv[16];
        #pragma unroll
        for (int q = 0; q < 4; ++q) {
            const float4 v =
                *reinterpret_cast<const float4*>(&h[cur][hoff + q * 4]);
            hv[q * 4 + 0] = v.x; hv[q * 4 + 1] = v.y;
            hv[q * 4 + 2] = v.z; hv[q * 4 + 3] = v.w;
        }

        float a0 = 0.f, a1 = 0.f, a2 = 0.f, a3 = 0.f;
        #pragma unroll
        for (int kk = 0; kk < 16; ++kk) {
            a0 += hv[kk] * w[0][kk];
            a1 += hv[kk] * w[1][kk];
            a2 += hv[kk] * w[2][kk];
            a3 += hv[kk] * w[3][kk];
        }

        // reduce over the 8 k-groups (lane bits 3-5)
        #pragma unroll
        for (int m = 8; m <= 32; m <<= 1) {
            a0 += __shfl_xor(a0, m, 64);
            a1 += __shfl_xor(a1, m, 64);
            a2 += __shfl_xor(a2, m, 64);
            a3 += __shfl_xor(a3, m, 64);
        }

        if (writer) {
            const float4 hold =
                *reinterpret_cast<const float4*>(&h[cur][woff]);
            float4 nh;
            nh.x = (1.f - LEAK) * hold.x + LEAK * fast_tanh(u_cur.x + a0);
            nh.y = (1.f - LEAK) * hold.y + LEAK * fast_tanh(u_cur.y + a1);
            nh.z = (1.f - LEAK) * hold.z + LEAK * fast_tanh(u_cur.z + a2);
            nh.w = (1.f - LEAK) * hold.w + LEAK * fast_tanh(u_cur.w + a3);
            *reinterpret_cast<float4*>(&out[t * RSZ + r0]) = nh;  // u_t consumed
            *reinterpret_cast<float4*>(&h[cur ^ 1][woff]) = nh;
        }
        u_cur = u_next;
        cur ^= 1;
        __syncthreads();
    }
}

extern "C" void kernel_launch(void* const* d_in, const int* in_sizes, int n_in,
                              void* d_out, int out_size, void* d_ws, size_t ws_size,
                              hipStream_t stream) {
    const float* x     = (const float*)d_in[0];
    const float* w_in  = (const float*)d_in[1];
    const float* w_res = (const float*)d_in[2];
    float* out = (float*)d_out;

    proj_kernel<<<(BATCH * SEQ) / 32, 256, 0, stream>>>(x, w_in, out);
    scan_kernel<<<BATCH, 256, 0, stream>>>(w_res, out);
}

// Round 2
// 2617.514 us; speedup vs baseline: 1.3144x; 1.3144x over previous
//
#include <hip/hip_runtime.h>

#define BATCH 64
#define SEQ   4096
#define ISZ   64
#define RSZ   128
constexpr float LEAK = 0.5f;

__device__ __forceinline__ float fast_tanh(float x) {
    float e = __expf(2.0f * x);
    return 1.0f - 2.0f / (e + 1.0f);
}

// ---------------------------------------------------------------------------
// Kernel 1: projection. out[row][r] = tanh(sum_j x[row][j] * w_in[r][j])
// rows = BATCH*SEQ flattened. 32 rows per block, 256 threads.
// ---------------------------------------------------------------------------
__global__ __launch_bounds__(256) void proj_kernel(
        const float* __restrict__ x, const float* __restrict__ w_in,
        float* __restrict__ out) {
    __shared__ float wT[ISZ][RSZ];   // 32 KB, transposed W_in: [j][r]
    __shared__ float xs[32][ISZ];    // 8 KB

    const int tid = threadIdx.x;

    for (int idx = tid; idx < RSZ * ISZ / 4; idx += 256) {
        const int r  = idx >> 4;
        const int j4 = (idx & 15) << 2;
        const float4 v = reinterpret_cast<const float4*>(w_in)[idx];
        wT[j4 + 0][r] = v.x; wT[j4 + 1][r] = v.y;
        wT[j4 + 2][r] = v.z; wT[j4 + 3][r] = v.w;
    }
    const long row0 = (long)blockIdx.x * 32;
    #pragma unroll
    for (int q = 0; q < 2; ++q) {
        const int idx = tid + q * 256;
        reinterpret_cast<float4*>(&xs[0][0])[idx] =
            reinterpret_cast<const float4*>(x + row0 * ISZ)[idx];
    }
    __syncthreads();

    const int rq = tid & 31;
    const int rp = tid >> 5;
    const int r0 = rq << 2;
    const int ra = rp << 2;

    float acc[4][4] = {};
    #pragma unroll
    for (int j4 = 0; j4 < ISZ; j4 += 4) {
        float4 xv[4];
        #pragma unroll
        for (int m = 0; m < 4; ++m)
            xv[m] = *reinterpret_cast<const float4*>(&xs[ra + m][j4]);
        #pragma unroll
        for (int k = 0; k < 4; ++k) {
            const float4 w = *reinterpret_cast<const float4*>(&wT[j4 + k][r0]);
            #pragma unroll
            for (int m = 0; m < 4; ++m) {
                const float xm = k == 0 ? xv[m].x : k == 1 ? xv[m].y
                               : k == 2 ? xv[m].z : xv[m].w;
                acc[m][0] += xm * w.x; acc[m][1] += xm * w.y;
                acc[m][2] += xm * w.z; acc[m][3] += xm * w.w;
            }
        }
    }
    #pragma unroll
    for (int m = 0; m < 4; ++m) {
        float4 o;
        o.x = fast_tanh(acc[m][0]); o.y = fast_tanh(acc[m][1]);
        o.z = fast_tanh(acc[m][2]); o.w = fast_tanh(acc[m][3]);
        *reinterpret_cast<float4*>(&out[(row0 + ra + m) * RSZ + r0]) = o;
    }
}

// ---------------------------------------------------------------------------
// Kernel 2: sequential scan. One block per batch, 256 threads = 4 waves.
// Thread (wave, rs, kg): partial dots for rows r0..r0+3 (r0 = wave*32+rs*4)
// over K-slice kg*16..+15. Butterfly reduce over kg (masks 8,16,32).
// Lanes kg<4 own output element r0+kg: tanh + global store + LDS h write.
// Raw s_barrier + lgkmcnt(0)-only wait: global stores are NOT drained on the
// barrier (the __syncthreads vmcnt(0) drain was ~60% of round-1's step time).
// ---------------------------------------------------------------------------
__global__ __launch_bounds__(256) void scan_kernel(
        const float* __restrict__ w_res, float* __restrict__ io) {
    __shared__ float h[2][8 * 20];        // padded: word = (e>>4)*20 + (e&15)

    const int tid  = threadIdx.x;
    const int lane = tid & 63;
    const int wave = tid >> 6;
    const int rs   = lane & 7;            // lane bits 0-2
    const int kg   = lane >> 3;           // lane bits 3-5 -> shfl masks 8,16,32
    const int r0   = wave * 32 + rs * 4;
    const int k0   = kg * 16;

    // W_res slice -> registers: rows r0..r0+3, cols k0..k0+15 (64 VGPRs)
    float w[4][16];
    #pragma unroll
    for (int rr = 0; rr < 4; ++rr) {
        #pragma unroll
        for (int kk = 0; kk < 16; kk += 4) {
            const float4 v = *reinterpret_cast<const float4*>(
                &w_res[(r0 + rr) * RSZ + k0 + kk]);
            w[rr][kk + 0] = v.x; w[rr][kk + 1] = v.y;
            w[rr][kk + 2] = v.z; w[rr][kk + 3] = v.w;
        }
    }

    for (int i = tid; i < 2 * 8 * 20; i += 256) (&h[0][0])[i] = 0.0f;

    float* const out = io + (long)blockIdx.x * (SEQ * RSZ);
    const bool wr   = (kg < 4);
    const int  hoff = kg * 20;                                    // read base
    const int  woff = (2 * wave + (rs >> 2)) * 20 + ((rs & 3) * 4 + kg);
    const int  gidx = r0 + kg;            // owned element (valid when wr)

    float u_cur = 0.f, u_next = 0.f, hreg = 0.f;
    if (wr) u_cur = out[gidx];
    __syncthreads();

    #define STEP(BUF, TT)                                                     \
    {                                                                         \
        if (wr && (TT) + 1 < SEQ) u_next = out[((TT) + 1) * RSZ + gidx];      \
        float hv[16];                                                         \
        _Pragma("unroll")                                                     \
        for (int q = 0; q < 4; ++q) {                                         \
            const float4 v =                                                  \
                *reinterpret_cast<const float4*>(&h[BUF][hoff + q * 4]);      \
            hv[q * 4 + 0] = v.x; hv[q * 4 + 1] = v.y;                         \
            hv[q * 4 + 2] = v.z; hv[q * 4 + 3] = v.w;                         \
        }                                                                     \
        float a0 = 0.f, a1 = 0.f, a2 = 0.f, a3 = 0.f;                         \
        _Pragma("unroll")                                                     \
        for (int kk = 0; kk < 16; ++kk) {                                     \
            a0 += hv[kk] * w[0][kk];                                          \
            a1 += hv[kk] * w[1][kk];                                          \
            a2 += hv[kk] * w[2][kk];                                          \
            a3 += hv[kk] * w[3][kk];                                          \
        }                                                                     \
        _Pragma("unroll")                                                     \
        for (int m = 8; m <= 32; m <<= 1) {                                   \
            a0 += __shfl_xor(a0, m, 64);                                      \
            a1 += __shfl_xor(a1, m, 64);                                      \
            a2 += __shfl_xor(a2, m, 64);                                      \
            a3 += __shfl_xor(a3, m, 64);                                      \
        }                                                                     \
        if (wr) {                                                             \
            const float a = kg == 0 ? a0 : kg == 1 ? a1 : kg == 2 ? a2 : a3;  \
            const float nh =                                                  \
                (1.f - LEAK) * hreg + LEAK * fast_tanh(u_cur + a);            \
            out[(TT) * RSZ + gidx] = nh;                                      \
            h[1 - (BUF)][woff] = nh;                                          \
            hreg = nh;                                                        \
        }                                                                     \
        asm volatile("s_waitcnt lgkmcnt(0)" ::: "memory");                    \
        __builtin_amdgcn_s_barrier();                                         \
        asm volatile("" ::: "memory");                                        \
        u_cur = u_next;                                                       \
    }

    for (int t = 0; t < SEQ; t += 2) {
        STEP(0, t)
        STEP(1, t + 1)
    }
    #undef STEP
}

extern "C" void kernel_launch(void* const* d_in, const int* in_sizes, int n_in,
                              void* d_out, int out_size, void* d_ws, size_t ws_size,
                              hipStream_t stream) {
    const float* x     = (const float*)d_in[0];
    const float* w_in  = (const float*)d_in[1];
    const float* w_res = (const float*)d_in[2];
    float* out = (float*)d_out;

    proj_kernel<<<(BATCH * SEQ) / 32, 256, 0, stream>>>(x, w_in, out);
    scan_kernel<<<BATCH, 256, 0, stream>>>(w_res, out);
}

// Round 3
// 2150.842 us; speedup vs baseline: 1.5996x; 1.2170x over previous
//
#include <hip/hip_runtime.h>

#define BATCH 64
#define SEQ   4096
#define ISZ   64
#define RSZ   128
constexpr float LEAK = 0.5f;

__device__ __forceinline__ float fast_tanh(float x) {
    float e = __expf(2.0f * x);
    return 1.0f - 2.0f / (e + 1.0f);
}

// xor-1 pair sum via DPP quad_perm [1,0,3,2] — single VALU op, no LDS/DS.
__device__ __forceinline__ float xor1_add(float x) {
#if __has_builtin(__builtin_amdgcn_update_dpp)
    int y = __builtin_amdgcn_update_dpp(0, __builtin_bit_cast(int, x),
                                        0xB1, 0xF, 0xF, true);
    return x + __builtin_bit_cast(float, y);
#else
    return x + __shfl_xor(x, 1, 64);
#endif
}

// ---------------------------------------------------------------------------
// Kernel 1: projection. out[row][r] = tanh(sum_j x[row][j] * w_in[r][j])
// rows = BATCH*SEQ flattened. 32 rows per block, 256 threads.
// ---------------------------------------------------------------------------
__global__ __launch_bounds__(256) void proj_kernel(
        const float* __restrict__ x, const float* __restrict__ w_in,
        float* __restrict__ out) {
    __shared__ float wT[ISZ][RSZ];   // 32 KB, transposed W_in: [j][r]
    __shared__ float xs[32][ISZ];    // 8 KB

    const int tid = threadIdx.x;

    for (int idx = tid; idx < RSZ * ISZ / 4; idx += 256) {
        const int r  = idx >> 4;
        const int j4 = (idx & 15) << 2;
        const float4 v = reinterpret_cast<const float4*>(w_in)[idx];
        wT[j4 + 0][r] = v.x; wT[j4 + 1][r] = v.y;
        wT[j4 + 2][r] = v.z; wT[j4 + 3][r] = v.w;
    }
    const long row0 = (long)blockIdx.x * 32;
    #pragma unroll
    for (int q = 0; q < 2; ++q) {
        const int idx = tid + q * 256;
        reinterpret_cast<float4*>(&xs[0][0])[idx] =
            reinterpret_cast<const float4*>(x + row0 * ISZ)[idx];
    }
    __syncthreads();

    const int rq = tid & 31;
    const int rp = tid >> 5;
    const int r0 = rq << 2;
    const int ra = rp << 2;

    float acc[4][4] = {};
    #pragma unroll
    for (int j4 = 0; j4 < ISZ; j4 += 4) {
        float4 xv[4];
        #pragma unroll
        for (int m = 0; m < 4; ++m)
            xv[m] = *reinterpret_cast<const float4*>(&xs[ra + m][j4]);
        #pragma unroll
        for (int k = 0; k < 4; ++k) {
            const float4 w = *reinterpret_cast<const float4*>(&wT[j4 + k][r0]);
            #pragma unroll
            for (int m = 0; m < 4; ++m) {
                const float xm = k == 0 ? xv[m].x : k == 1 ? xv[m].y
                               : k == 2 ? xv[m].z : xv[m].w;
                acc[m][0] += xm * w.x; acc[m][1] += xm * w.y;
                acc[m][2] += xm * w.z; acc[m][3] += xm * w.w;
            }
        }
    }
    #pragma unroll
    for (int m = 0; m < 4; ++m) {
        float4 o;
        o.x = fast_tanh(acc[m][0]); o.y = fast_tanh(acc[m][1]);
        o.z = fast_tanh(acc[m][2]); o.w = fast_tanh(acc[m][3]);
        *reinterpret_cast<float4*>(&out[(row0 + ra + m) * RSZ + r0]) = o;
    }
}

// ---------------------------------------------------------------------------
// Kernel 2: sequential scan. One block per batch, 256 threads = 4 waves.
// Lane pair (2l, 2l+1) of wave w owns output r = w*32 + l: each lane does the
// dot over one 64-wide k-half (64 FMA, W slice in 64 VGPRs), then ONE xor-1
// DPP add completes the sum (no ds_bpermute tree — round-2's ~400 cyc shuffle
// chain is gone). Both lanes compute nh; even lane writes LDS h, odd lane
// writes global. h double-buffered, k-half stride padded to 68 words so the
// two broadcast address groups per ds_read_b128 hit disjoint bank quads.
// Raw s_barrier + lgkmcnt(0)-only wait (global stores never drained).
// u prefetched 2 steps ahead to cover HBM latency.
// ---------------------------------------------------------------------------
__global__ __launch_bounds__(256) void scan_kernel(
        const float* __restrict__ w_res, float* __restrict__ io) {
    __shared__ float h[2][136];          // element e -> word e + ((e>>6)<<2)

    const int tid   = threadIdx.x;
    const int lane  = tid & 63;
    const int wave  = tid >> 6;
    const int rloc  = lane >> 1;         // 0..31
    const int khalf = lane & 1;          // which 64-wide k half
    const int r     = wave * 32 + rloc;  // owned output element
    const int kbase = khalf * 64;

    // W_res row slice -> 64 VGPRs: w_res[r][kbase .. kbase+63]
    float w[64];
    #pragma unroll
    for (int kk = 0; kk < 64; kk += 4) {
        const float4 v = *reinterpret_cast<const float4*>(
            &w_res[r * RSZ + kbase + kk]);
        w[kk + 0] = v.x; w[kk + 1] = v.y; w[kk + 2] = v.z; w[kk + 3] = v.w;
    }

    for (int i = tid; i < 2 * 136; i += 256) (&h[0][0])[i] = 0.0f;

    float* const out  = io + (long)blockIdx.x * (SEQ * RSZ);
    const int  hread  = khalf * 68;              // word base for k-half reads
    const int  hwr    = r + ((r >> 6) << 2);     // padded word of own element

    float u0 = out[r];                           // t = 0 (pair-shared addr)
    float u1 = out[RSZ + r];                     // t = 1
    float u2 = 0.f;
    float hreg = 0.f;
    __syncthreads();

    #define STEP(BUF, TT)                                                     \
    {                                                                         \
        if ((TT) + 2 < SEQ) u2 = out[((TT) + 2) * RSZ + r];                   \
        float a0 = 0.f, a1 = 0.f, a2 = 0.f, a3 = 0.f;                         \
        _Pragma("unroll")                                                     \
        for (int q = 0; q < 16; ++q) {                                        \
            const float4 hv =                                                 \
                *reinterpret_cast<const float4*>(&h[BUF][hread + q * 4]);     \
            float* acc = (q & 3) == 0 ? &a0 : (q & 3) == 1 ? &a1              \
                       : (q & 3) == 2 ? &a2 : &a3;                            \
            *acc = fmaf(hv.x, w[q * 4 + 0], *acc);                            \
            *acc = fmaf(hv.y, w[q * 4 + 1], *acc);                            \
            *acc = fmaf(hv.z, w[q * 4 + 2], *acc);                            \
            *acc = fmaf(hv.w, w[q * 4 + 3], *acc);                            \
        }                                                                     \
        float asum = (a0 + a1) + (a2 + a3);                                   \
        asum = xor1_add(asum);                                                \
        const float nh =                                                      \
            (1.f - LEAK) * hreg + LEAK * fast_tanh(u0 + asum);                \
        hreg = nh;                                                            \
        if (khalf == 0) h[1 - (BUF)][hwr] = nh;                               \
        else            out[(TT) * RSZ + r] = nh;                             \
        asm volatile("s_waitcnt lgkmcnt(0)" ::: "memory");                    \
        __builtin_amdgcn_s_barrier();                                         \
        asm volatile("" ::: "memory");                                        \
        u0 = u1; u1 = u2;                                                     \
    }

    for (int t = 0; t < SEQ; t += 2) {
        STEP(0, t)
        STEP(1, t + 1)
    }
    #undef STEP
}

extern "C" void kernel_launch(void* const* d_in, const int* in_sizes, int n_in,
                              void* d_out, int out_size, void* d_ws, size_t ws_size,
                              hipStream_t stream) {
    const float* x     = (const float*)d_in[0];
    const float* w_in  = (const float*)d_in[1];
    const float* w_res = (const float*)d_in[2];
    float* out = (float*)d_out;

    proj_kernel<<<(BATCH * SEQ) / 32, 256, 0, stream>>>(x, w_in, out);
    scan_kernel<<<BATCH, 256, 0, stream>>>(w_res, out);
}

// Round 4
// 2015.293 us; speedup vs baseline: 1.7071x; 1.0673x over previous
//
#include <hip/hip_runtime.h>

#define BATCH 64
#define SEQ   4096
#define ISZ   64
#define RSZ   128
constexpr float LEAK = 0.5f;

__device__ __forceinline__ float fast_tanh(float x) {
    float e = __expf(2.0f * x);
    return 1.0f - 2.0f / (e + 1.0f);
}

// x + cross-lane(x) via DPP — pure VALU, no DS ops.
// ctrl: 0xB1 = quad_perm[1,0,3,2] (xor1), 0x4E = quad_perm[2,3,0,1] (xor2),
//       0x141 = row_half_mirror (xor7; ≡ xor4 once quads are uniform).
template <int CTRL>
__device__ __forceinline__ float dpp_add(float x) {
    int y = __builtin_amdgcn_update_dpp(0, __builtin_bit_cast(int, x),
                                        CTRL, 0xF, 0xF, true);
    return x + __builtin_bit_cast(float, y);
}

// ---------------------------------------------------------------------------
// Kernel 1: projection. out[row][r] = tanh(sum_j x[row][j] * w_in[r][j])
// ---------------------------------------------------------------------------
__global__ __launch_bounds__(256) void proj_kernel(
        const float* __restrict__ x, const float* __restrict__ w_in,
        float* __restrict__ out) {
    __shared__ float wT[ISZ][RSZ];
    __shared__ float xs[32][ISZ];

    const int tid = threadIdx.x;

    for (int idx = tid; idx < RSZ * ISZ / 4; idx += 256) {
        const int r  = idx >> 4;
        const int j4 = (idx & 15) << 2;
        const float4 v = reinterpret_cast<const float4*>(w_in)[idx];
        wT[j4 + 0][r] = v.x; wT[j4 + 1][r] = v.y;
        wT[j4 + 2][r] = v.z; wT[j4 + 3][r] = v.w;
    }
    const long row0 = (long)blockIdx.x * 32;
    #pragma unroll
    for (int q = 0; q < 2; ++q) {
        const int idx = tid + q * 256;
        reinterpret_cast<float4*>(&xs[0][0])[idx] =
            reinterpret_cast<const float4*>(x + row0 * ISZ)[idx];
    }
    __syncthreads();

    const int rq = tid & 31;
    const int rp = tid >> 5;
    const int r0 = rq << 2;
    const int ra = rp << 2;

    float acc[4][4] = {};
    #pragma unroll
    for (int j4 = 0; j4 < ISZ; j4 += 4) {
        float4 xv[4];
        #pragma unroll
        for (int m = 0; m < 4; ++m)
            xv[m] = *reinterpret_cast<const float4*>(&xs[ra + m][j4]);
        #pragma unroll
        for (int k = 0; k < 4; ++k) {
            const float4 w = *reinterpret_cast<const float4*>(&wT[j4 + k][r0]);
            #pragma unroll
            for (int m = 0; m < 4; ++m) {
                const float xm = k == 0 ? xv[m].x : k == 1 ? xv[m].y
                               : k == 2 ? xv[m].z : xv[m].w;
                acc[m][0] += xm * w.x; acc[m][1] += xm * w.y;
                acc[m][2] += xm * w.z; acc[m][3] += xm * w.w;
            }
        }
    }
    #pragma unroll
    for (int m = 0; m < 4; ++m) {
        float4 o;
        o.x = fast_tanh(acc[m][0]); o.y = fast_tanh(acc[m][1]);
        o.z = fast_tanh(acc[m][2]); o.w = fast_tanh(acc[m][3]);
        *reinterpret_cast<float4*>(&out[(row0 + ra + m) * RSZ + r0]) = o;
    }
}

// ---------------------------------------------------------------------------
// Kernel 2: sequential scan. One block per batch, 256 threads = 4 waves.
// Wave w owns outputs [32w, 32w+32). Lane = (grp, sl): grp = lane>>3 owns the
// 4 outputs r0 = 32w + 4*grp .. +3; sl = lane&7 covers k-slice [16sl, 16sl+16).
// Per lane per step: 4 ds_read_b128 (vs round-3's 16), 64 FMA, 3-level DPP
// reduce over sl (xor1, xor2, xor7/half_mirror), 4 tanh; lane sl==0 does ONE
// ds_write_b128 of the group's nh, lane sl==1 ONE global_store_dwordx4.
// h double-buffered; slice stride padded to 20 words -> 8 slice bases on 8
// distinct banks, 16B aligned, broadcast reads conflict-free.
// Raw s_barrier + lgkmcnt(0)-only wait; u prefetched 2 steps ahead.
// ---------------------------------------------------------------------------
__global__ __launch_bounds__(256) void scan_kernel(
        const float* __restrict__ w_res, float* __restrict__ io) {
    __shared__ float h[2][160];          // element k -> word 20*(k>>4)+(k&15)

    const int tid  = threadIdx.x;
    const int lane = tid & 63;
    const int wave = tid >> 6;
    const int grp  = lane >> 3;          // 8 output groups of 4
    const int sl   = lane & 7;           // 8 k-slices of 16
    const int r0   = wave * 32 + grp * 4;
    const int kb   = sl * 16;

    // W_res rows r0..r0+3, cols kb..kb+15 -> 64 VGPRs
    float w[4][16];
    #pragma unroll
    for (int rr = 0; rr < 4; ++rr) {
        #pragma unroll
        for (int kk = 0; kk < 16; kk += 4) {
            const float4 v = *reinterpret_cast<const float4*>(
                &w_res[(r0 + rr) * RSZ + kb + kk]);
            w[rr][kk + 0] = v.x; w[rr][kk + 1] = v.y;
            w[rr][kk + 2] = v.z; w[rr][kk + 3] = v.w;
        }
    }

    for (int i = tid; i < 2 * 160; i += 256) (&h[0][0])[i] = 0.0f;

    float* const out  = io + (long)blockIdx.x * (SEQ * RSZ);
    const int  rbase  = 20 * sl;                       // read word base
    const int  wbase  = 20 * (r0 >> 4) + (r0 & 15);    // write word base

    float4 u0 = *reinterpret_cast<const float4*>(&out[r0]);
    float4 u1 = *reinterpret_cast<const float4*>(&out[RSZ + r0]);
    float4 u2 = {0, 0, 0, 0};
    float4 hreg = {0, 0, 0, 0};
    __syncthreads();

    #define STEP(BUF, TT)                                                     \
    {                                                                         \
        if ((TT) + 2 < SEQ)                                                   \
            u2 = *reinterpret_cast<const float4*>(                            \
                &out[((TT) + 2) * RSZ + r0]);                                 \
        float a0 = 0.f, a1 = 0.f, a2 = 0.f, a3 = 0.f;                         \
        _Pragma("unroll")                                                     \
        for (int q = 0; q < 4; ++q) {                                         \
            const float4 hv =                                                 \
                *reinterpret_cast<const float4*>(&h[BUF][rbase + q * 4]);     \
            a0 = fmaf(hv.x, w[0][q*4+0], a0); a0 = fmaf(hv.y, w[0][q*4+1], a0);\
            a0 = fmaf(hv.z, w[0][q*4+2], a0); a0 = fmaf(hv.w, w[0][q*4+3], a0);\
            a1 = fmaf(hv.x, w[1][q*4+0], a1); a1 = fmaf(hv.y, w[1][q*4+1], a1);\
            a1 = fmaf(hv.z, w[1][q*4+2], a1); a1 = fmaf(hv.w, w[1][q*4+3], a1);\
            a2 = fmaf(hv.x, w[2][q*4+0], a2); a2 = fmaf(hv.y, w[2][q*4+1], a2);\
            a2 = fmaf(hv.z, w[2][q*4+2], a2); a2 = fmaf(hv.w, w[2][q*4+3], a2);\
            a3 = fmaf(hv.x, w[3][q*4+0], a3); a3 = fmaf(hv.y, w[3][q*4+1], a3);\
            a3 = fmaf(hv.z, w[3][q*4+2], a3); a3 = fmaf(hv.w, w[3][q*4+3], a3);\
        }                                                                     \
        a0 = dpp_add<0xB1>(a0);  a1 = dpp_add<0xB1>(a1);                      \
        a2 = dpp_add<0xB1>(a2);  a3 = dpp_add<0xB1>(a3);                      \
        a0 = dpp_add<0x4E>(a0);  a1 = dpp_add<0x4E>(a1);                      \
        a2 = dpp_add<0x4E>(a2);  a3 = dpp_add<0x4E>(a3);                      \
        a0 = dpp_add<0x141>(a0); a1 = dpp_add<0x141>(a1);                     \
        a2 = dpp_add<0x141>(a2); a3 = dpp_add<0x141>(a3);                     \
        float4 nh;                                                            \
        nh.x = (1.f - LEAK) * hreg.x + LEAK * fast_tanh(u0.x + a0);           \
        nh.y = (1.f - LEAK) * hreg.y + LEAK * fast_tanh(u0.y + a1);           \
        nh.z = (1.f - LEAK) * hreg.z + LEAK * fast_tanh(u0.z + a2);           \
        nh.w = (1.f - LEAK) * hreg.w + LEAK * fast_tanh(u0.w + a3);           \
        hreg = nh;                                                            \
        if (sl == 0)                                                          \
            *reinterpret_cast<float4*>(&h[1 - (BUF)][wbase]) = nh;            \
        else if (sl == 1)                                                     \
            *reinterpret_cast<float4*>(&out[(TT) * RSZ + r0]) = nh;           \
        asm volatile("s_waitcnt lgkmcnt(0)" ::: "memory");                    \
        __builtin_amdgcn_s_barrier();                                         \
        asm volatile("" ::: "memory");                                        \
        u0 = u1; u1 = u2;                                                     \
    }

    for (int t = 0; t < SEQ; t += 2) {
        STEP(0, t)
        STEP(1, t + 1)
    }
    #undef STEP
}

extern "C" void kernel_launch(void* const* d_in, const int* in_sizes, int n_in,
                              void* d_out, int out_size, void* d_ws, size_t ws_size,
                              hipStream_t stream) {
    const float* x     = (const float*)d_in[0];
    const float* w_in  = (const float*)d_in[1];
    const float* w_res = (const float*)d_in[2];
    float* out = (float*)d_out;

    proj_kernel<<<(BATCH * SEQ) / 32, 256, 0, stream>>>(x, w_in, out);
    scan_kernel<<<BATCH, 256, 0, stream>>>(w_res, out);
}

// Round 6
// 1539.620 us; speedup vs baseline: 2.2346x; 1.3090x over previous
//
#include <hip/hip_runtime.h>

#define BATCH 64
#define SEQ   4096
#define ISZ   64
#define RSZ   128
constexpr float LEAK = 0.5f;

typedef float f32x4_t __attribute__((ext_vector_type(4)));

__device__ __forceinline__ float fast_tanh(float x) {
    float e = __expf(2.0f * x);
    return 1.0f - 2.0f / (e + 1.0f);
}

// x + cross-lane(x) via DPP — pure VALU, no DS ops.
// 0xB1 = quad_perm[1,0,3,2] (xor1), 0x4E = quad_perm[2,3,0,1] (xor2),
// 0x141 = row_half_mirror (xor7; ≡ xor4 once quads are uniform).
template <int CTRL>
__device__ __forceinline__ float dpp_add(float x) {
    int y = __builtin_amdgcn_update_dpp(0, __builtin_bit_cast(int, x),
                                        CTRL, 0xF, 0xF, true);
    return x + __builtin_bit_cast(float, y);
}

// ---------------------------------------------------------------------------
// Kernel 1: projection. out[row][r] = tanh(sum_j x[row][j] * w_in[r][j])
// ---------------------------------------------------------------------------
__global__ __launch_bounds__(256) void proj_kernel(
        const float* __restrict__ x, const float* __restrict__ w_in,
        float* __restrict__ out) {
    __shared__ float wT[ISZ][RSZ];
    __shared__ float xs[32][ISZ];

    const int tid = threadIdx.x;

    for (int idx = tid; idx < RSZ * ISZ / 4; idx += 256) {
        const int r  = idx >> 4;
        const int j4 = (idx & 15) << 2;
        const float4 v = reinterpret_cast<const float4*>(w_in)[idx];
        wT[j4 + 0][r] = v.x; wT[j4 + 1][r] = v.y;
        wT[j4 + 2][r] = v.z; wT[j4 + 3][r] = v.w;
    }
    const long row0 = (long)blockIdx.x * 32;
    #pragma unroll
    for (int q = 0; q < 2; ++q) {
        const int idx = tid + q * 256;
        reinterpret_cast<float4*>(&xs[0][0])[idx] =
            reinterpret_cast<const float4*>(x + row0 * ISZ)[idx];
    }
    __syncthreads();

    const int rq = tid & 31;
    const int rp = tid >> 5;
    const int r0 = rq << 2;
    const int ra = rp << 2;

    float acc[4][4] = {};
    #pragma unroll
    for (int j4 = 0; j4 < ISZ; j4 += 4) {
        float4 xv[4];
        #pragma unroll
        for (int m = 0; m < 4; ++m)
            xv[m] = *reinterpret_cast<const float4*>(&xs[ra + m][j4]);
        #pragma unroll
        for (int k = 0; k < 4; ++k) {
            const float4 w = *reinterpret_cast<const float4*>(&wT[j4 + k][r0]);
            #pragma unroll
            for (int m = 0; m < 4; ++m) {
                const float xm = k == 0 ? xv[m].x : k == 1 ? xv[m].y
                               : k == 2 ? xv[m].z : xv[m].w;
                acc[m][0] += xm * w.x; acc[m][1] += xm * w.y;
                acc[m][2] += xm * w.z; acc[m][3] += xm * w.w;
            }
        }
    }
    #pragma unroll
    for (int m = 0; m < 4; ++m) {
        float4 o;
        o.x = fast_tanh(acc[m][0]); o.y = fast_tanh(acc[m][1]);
        o.z = fast_tanh(acc[m][2]); o.w = fast_tanh(acc[m][3]);
        *reinterpret_cast<float4*>(&out[(row0 + ra + m) * RSZ + r0]) = o;
    }
}

// ---------------------------------------------------------------------------
// Kernel 2: sequential scan. One block per batch, 256 threads = 4 waves.
// Decomposition as round 4: wave owns 32 outputs; lane (grp = lane>>3,
// sl = lane&7) does rows r0..r0+3 x k-slice [16sl,16sl+16): 4 ds_read_b128,
// 64 FMA, 3-level DPP reduce, fused leak+tanh.
// No global store inside the step (a per-step HBM store sat in the in-order
// vmcnt FIFO ahead of the u-prefetch loads, forcing a store-retire wait every
// step). nh is staged to a 16-slot LDS ring (slot = t&15, sl==1 lanes, one
// ds_write_b128/wave); every 8 steps all 256 threads flush the just-written
// half with 1 coalesced ds_read_b128 + 1 nontemporal global_store_dwordx4.
// The 16-slot double ring puts >=8 barriered steps between a flush-read and
// the next write to that slot; flushed range [t0,t0+7] is disjoint from
// in-flight u loads (>= t0+12). u prefetch 4 steps deep (static ring).
// Raw s_barrier + lgkmcnt(0)-only wait as before.
// ---------------------------------------------------------------------------
__global__ __launch_bounds__(256) void scan_kernel(
        const float* __restrict__ w_res, float* __restrict__ io) {
    __shared__ float h[2][160];          // element k -> word 20*(k>>4)+(k&15)
    __shared__ float stage[16 * 128];    // 8 KB ring, slot = t & 15

    const int tid  = threadIdx.x;
    const int lane = tid & 63;
    const int wave = tid >> 6;
    const int grp  = lane >> 3;          // 8 output groups of 4
    const int sl   = lane & 7;           // 8 k-slices of 16
    const int r0   = wave * 32 + grp * 4;
    const int kb   = sl * 16;

    // W_res rows r0..r0+3, cols kb..kb+15 -> 64 VGPRs
    float w[4][16];
    #pragma unroll
    for (int rr = 0; rr < 4; ++rr) {
        #pragma unroll
        for (int kk = 0; kk < 16; kk += 4) {
            const float4 v = *reinterpret_cast<const float4*>(
                &w_res[(r0 + rr) * RSZ + kb + kk]);
            w[rr][kk + 0] = v.x; w[rr][kk + 1] = v.y;
            w[rr][kk + 2] = v.z; w[rr][kk + 3] = v.w;
        }
    }

    for (int i = tid; i < 2 * 160; i += 256) (&h[0][0])[i] = 0.0f;

    float* const out  = io + (long)blockIdx.x * (SEQ * RSZ);
    const int  rbase  = 20 * sl;                       // h read word base
    const int  wbase  = 20 * (r0 >> 4) + (r0 & 15);    // h write word base

    // 4-deep u prefetch ring (all indices compile-time)
    float4 u[4];
    #pragma unroll
    for (int s = 0; s < 4; ++s)
        u[s] = *reinterpret_cast<const float4*>(&out[s * RSZ + r0]);
    float4 hreg = {0.f, 0.f, 0.f, 0.f};
    __syncthreads();

    // nh = 0.5*h + 0.5*tanh(v) = fma(0.5,h,0.5) - 1/(exp2(2*log2e*v)+1)
    #define ACT(HH, VV)                                                       \
        (fmaf(0.5f, (HH), 0.5f) -                                             \
         __builtin_amdgcn_rcpf(                                               \
             __builtin_amdgcn_exp2f((VV) * 2.885390082f) + 1.0f))

    #define STEP(S)                                                           \
    {                                                                         \
        const float4 uc = u[(S) & 3];                                         \
        if (t0 + (S) + 4 < SEQ)                                               \
            u[(S) & 3] = *reinterpret_cast<const float4*>(                    \
                &out[(t0 + (S) + 4) * RSZ + r0]);                             \
        float a0 = 0.f, a1 = 0.f, a2 = 0.f, a3 = 0.f;                         \
        _Pragma("unroll")                                                     \
        for (int q = 0; q < 4; ++q) {                                         \
            const float4 hv = *reinterpret_cast<const float4*>(               \
                &h[(S) & 1][rbase + q * 4]);                                  \
            a0 = fmaf(hv.x, w[0][q*4+0], a0); a0 = fmaf(hv.y, w[0][q*4+1], a0);\
            a0 = fmaf(hv.z, w[0][q*4+2], a0); a0 = fmaf(hv.w, w[0][q*4+3], a0);\
            a1 = fmaf(hv.x, w[1][q*4+0], a1); a1 = fmaf(hv.y, w[1][q*4+1], a1);\
            a1 = fmaf(hv.z, w[1][q*4+2], a1); a1 = fmaf(hv.w, w[1][q*4+3], a1);\
            a2 = fmaf(hv.x, w[2][q*4+0], a2); a2 = fmaf(hv.y, w[2][q*4+1], a2);\
            a2 = fmaf(hv.z, w[2][q*4+2], a2); a2 = fmaf(hv.w, w[2][q*4+3], a2);\
            a3 = fmaf(hv.x, w[3][q*4+0], a3); a3 = fmaf(hv.y, w[3][q*4+1], a3);\
            a3 = fmaf(hv.z, w[3][q*4+2], a3); a3 = fmaf(hv.w, w[3][q*4+3], a3);\
        }                                                                     \
        a0 = dpp_add<0xB1>(a0);  a1 = dpp_add<0xB1>(a1);                      \
        a2 = dpp_add<0xB1>(a2);  a3 = dpp_add<0xB1>(a3);                      \
        a0 = dpp_add<0x4E>(a0);  a1 = dpp_add<0x4E>(a1);                      \
        a2 = dpp_add<0x4E>(a2);  a3 = dpp_add<0x4E>(a3);                      \
        a0 = dpp_add<0x141>(a0); a1 = dpp_add<0x141>(a1);                     \
        a2 = dpp_add<0x141>(a2); a3 = dpp_add<0x141>(a3);                     \
        float4 nh;                                                            \
        nh.x = ACT(hreg.x, uc.x + a0);                                        \
        nh.y = ACT(hreg.y, uc.y + a1);                                        \
        nh.z = ACT(hreg.z, uc.z + a2);                                        \
        nh.w = ACT(hreg.w, uc.w + a3);                                        \
        hreg = nh;                                                            \
        if (sl == 0)                                                          \
            *reinterpret_cast<float4*>(&h[1 - ((S) & 1)][wbase]) = nh;        \
        else if (sl == 1)                                                     \
            *reinterpret_cast<float4*>(                                       \
                &stage[((t0 & 8) + (S)) * 128 + r0]) = nh;                    \
        asm volatile("s_waitcnt lgkmcnt(0)" ::: "memory");                    \
        __builtin_amdgcn_s_barrier();                                         \
        asm volatile("" ::: "memory");                                        \
    }

    const int fstep = tid >> 5;          // 0..7: which step of the half
    const int felem = (tid & 31) * 4;    // 0..124: element quad

    for (int t0 = 0; t0 < SEQ; t0 += 8) {
        STEP(0) STEP(1) STEP(2) STEP(3)
        STEP(4) STEP(5) STEP(6) STEP(7)
        // Flush this iteration's 8 staged steps: coalesced LDS read + NT store
        const f32x4_t v = *reinterpret_cast<const f32x4_t*>(
            &stage[((t0 & 8) + fstep) * 128 + felem]);
        __builtin_nontemporal_store(v,
            reinterpret_cast<f32x4_t*>(&out[(t0 + fstep) * RSZ + felem]));
    }
    #undef STEP
    #undef ACT
}

extern "C" void kernel_launch(void* const* d_in, const int* in_sizes, int n_in,
                              void* d_out, int out_size, void* d_ws, size_t ws_size,
                              hipStream_t stream) {
    const float* x     = (const float*)d_in[0];
    const float* w_in  = (const float*)d_in[1];
    const float* w_res = (const float*)d_in[2];
    float* out = (float*)d_out;

    proj_kernel<<<(BATCH * SEQ) / 32, 256, 0, stream>>>(x, w_in, out);
    scan_kernel<<<BATCH, 256, 0, stream>>>(w_res, out);
}